// Round 1
// baseline (162.537 us; speedup 1.0000x reference)
//
#include <hip/hip_runtime.h>

// SigKernel: X (32,256,8) f32, Y (32,256,8) f32 -> out (32,32) f32.
// refinement=1.0 => interpolation is identity; scale=1.0 => inc = dX . dY^T.
// Per pair (a,b): Goursat PDE wavefront over 256x256 grid, boundary = 1,
//   a_ij  = dot(dX[i-1], dY[j-1])   (8-dim)
//   f1 = 1 + a/2 + a^2/12,  f2 = 1 - a^2/12
//   K[i,j] = (K[i,j-1] + K[i-1,j]) * f1 - K[i-1,j-1] * f2
// Output = K[255,255].

#define LPTS 256
#define DIMS 8
#define MM   255   // LPTS-1 interior increments

__global__ __launch_bounds__(256) void sigker_antidiag(
    const float* __restrict__ X,
    const float* __restrict__ Y,
    float* __restrict__ out)
{
    const int pair = blockIdx.x;          // 0..1023
    const int ax = pair >> 5;             // X batch index
    const int by = pair & 31;             // Y batch index
    const int t  = threadIdx.x;           // 0..255 = grid row i

    // dY transposed: dYs[c][j] = Y[by][j+1][c] - Y[by][j][c].
    // Lane i reads dYs[c][d-i-1]: consecutive lanes -> consecutive addrs
    // -> 2 lanes/bank (free). Stride 256 floats per c-row.
    __shared__ float dYs[DIMS][LPTS];
    __shared__ float diag[3][LPTS];       // rotating antidiagonals

    const float* Xa = X + ax * (LPTS * DIMS);
    const float* Yb = Y + by * (LPTS * DIMS);

    // Per-thread fixed A-row: dx[c] = X[ax][t][c] - X[ax][t-1][c], used for
    // every cell in row t (t>=1).
    float dx[DIMS];
    if (t >= 1) {
        #pragma unroll
        for (int c = 0; c < DIMS; ++c)
            dx[c] = Xa[t * DIMS + c] - Xa[(t - 1) * DIMS + c];
    }

    // Cooperative transpose-load of dY increments (255*8 = 2040 values).
    for (int v = t; v < MM * DIMS; v += 256) {
        int j = v >> 3;
        int c = v & 7;
        dYs[c][j] = Yb[(j + 1) * DIMS + c] - Yb[j * DIMS + c];
    }

    // Antidiagonals d=0 and d=1.
    diag[0][t] = (t == 0) ? 1.0f : 0.0f;
    diag[1][t] = (t <= 1) ? 1.0f : 0.0f;
    __syncthreads();

    // March d = 2 .. 2*MM. One barrier per diagonal.
    for (int d = 2; d <= 2 * MM; ++d) {
        float* Kd  = diag[d % 3];
        const float* Km1 = diag[(d + 2) % 3];   // d-1
        const float* Km2 = diag[(d + 1) % 3];   // d-2
        const int j = d - t;
        if (t >= 1 && j >= 1 && j <= MM) {
            float a = 0.0f;
            #pragma unroll
            for (int c = 0; c < DIMS; ++c)
                a = fmaf(dx[c], dYs[c][j - 1], a);
            const float a2 = a * a;
            const float f1 = 1.0f + 0.5f * a + a2 * (1.0f / 12.0f);
            const float f2 = 1.0f - a2 * (1.0f / 12.0f);
            Kd[t] = (Km1[t] + Km1[t - 1]) * f1 - Km2[t - 1] * f2;
        } else if (t == 0 || j == 0) {
            Kd[t] = 1.0f;                       // boundary
        }
        __syncthreads();
    }

    // Last diagonal is d = 2*MM = 510; 510 % 3 == 0. K(255,255) at row 255,
    // written by this same thread (no extra barrier needed).
    if (t == MM) out[pair] = diag[(2 * MM) % 3][MM];
}

extern "C" void kernel_launch(void* const* d_in, const int* in_sizes, int n_in,
                              void* d_out, int out_size, void* d_ws, size_t ws_size,
                              hipStream_t stream)
{
    const float* X = (const float*)d_in[0];
    const float* Y = (const float*)d_in[1];
    float* out = (float*)d_out;
    (void)in_sizes; (void)n_in; (void)out_size; (void)d_ws; (void)ws_size;

    sigker_antidiag<<<dim3(32 * 32), dim3(256), 0, stream>>>(X, Y, out);
}

// Round 2
// 70.605 us; speedup vs baseline: 2.3021x; 2.3021x over previous
//
#include <hip/hip_runtime.h>

// SigKernel: X (32,256,8) f32, Y (32,256,8) f32 -> out (32,32) f32.
// refinement=1.0 => interpolation identity; scale=1.0 => a_ij = dot(dX[i-1], dY[j-1]).
// Goursat PDE on 256x256 grid, boundary K[i][0]=K[0][j]=1:
//   f1 = 1 + a/2 + a^2/12, f2 = 1 - a^2/12
//   K[i][j] = (K[i][j-1] + K[i-1][j])*f1 - K[i-1][j-1]*f2 ; out = K[255][255]
//
// Scheme: 1 wave per pair, lane l owns rows 4l+1..4l+4. Skewed column march:
// step s, lane l handles column j = s-l (4 cells). Inter-lane dep (row 4l from
// lane l-1, one step stale) via __shfl_up -- no barriers in the main loop.

#define MM   255          // interior increments per axis
#define RPL  4            // rows per lane
#define DYSTRIDE 9        // odd float stride -> conflict-free ds_read_b32

__global__ __launch_bounds__(64) void sigker_strip(
    const float* __restrict__ X,
    const float* __restrict__ Y,
    float* __restrict__ out)
{
    const int pair = blockIdx.x;      // 0..1023
    const int ax = pair >> 5;
    const int by = pair & 31;
    const int l  = threadIdx.x;       // 0..63

    __shared__ float dYs[MM * DYSTRIDE + 8];

    const float* Xa = X + ax * (256 * 8);
    const float* Yb = Y + by * (256 * 8);

    // Stage dY increments transystride-9: dYs[j*9 + c] = Y[j+1][c] - Y[j][c].
    for (int v = l; v < MM * 8; v += 64) {
        const int j = v >> 3, c = v & 7;
        dYs[j * DYSTRIDE + c] = Yb[(j + 1) * 8 + c] - Yb[j * 8 + c];
    }

    // Per-lane dX rows: row i = 4l + r + 1 (row 256 masked to zero).
    float dx[RPL][8];
    #pragma unroll
    for (int r = 0; r < RPL; ++r) {
        const int i = RPL * l + r + 1;
        if (i <= MM) {
            #pragma unroll
            for (int c = 0; c < 8; ++c)
                dx[r][c] = Xa[i * 8 + c] - Xa[(i - 1) * 8 + c];
        } else {
            #pragma unroll
            for (int c = 0; c < 8; ++c) dx[r][c] = 0.0f;
        }
    }

    __syncthreads();

    // K[r] = K[row_r][j-1]; upd = K[4l][j-1]. j=0 boundary = 1 everywhere.
    float K[RPL] = {1.0f, 1.0f, 1.0f, 1.0f};
    float upd = 1.0f;

    const int SMAX = MM + 63;         // s = 1 .. 318
    for (int s = 1; s <= SMAX; ++s) {
        // Lane l-1's row-4l value at column j (computed last step).
        float up = __shfl_up(K[RPL - 1], 1);
        if (l == 0) up = 1.0f;        // row 0 boundary

        const int j = s - l;
        int jj = j - 1;
        jj = jj < 0 ? 0 : (jj > MM - 1 ? MM - 1 : jj);   // clamp for idle lanes
        const float* __restrict__ dyp = dYs + jj * DYSTRIDE;
        float dy0 = dyp[0], dy1 = dyp[1], dy2 = dyp[2], dy3 = dyp[3];
        float dy4 = dyp[4], dy5 = dyp[5], dy6 = dyp[6], dy7 = dyp[7];

        if (j >= 1 && j <= MM) {
            float kup  = up;   // K[row_r - 1][j]
            float kupd = upd;  // K[row_r - 1][j-1]
            #pragma unroll
            for (int r = 0; r < RPL; ++r) {
                float a = dx[r][0] * dy0;
                a = fmaf(dx[r][1], dy1, a);
                a = fmaf(dx[r][2], dy2, a);
                a = fmaf(dx[r][3], dy3, a);
                a = fmaf(dx[r][4], dy4, a);
                a = fmaf(dx[r][5], dy5, a);
                a = fmaf(dx[r][6], dy6, a);
                a = fmaf(dx[r][7], dy7, a);
                const float a2 = a * a;
                const float f1 = fmaf(a2, 1.0f / 12.0f, fmaf(a, 0.5f, 1.0f));
                const float f2 = fmaf(a2, -1.0f / 12.0f, 1.0f);
                const float t  = kupd * f2;
                const float kn = fmaf(K[r] + kup, f1, -t);
                kupd = K[r];
                kup  = kn;
                K[r] = kn;
            }
            upd = up;
        }
    }

    // Row 255 = lane 63, r = 2; its K[2] last updated at j = 255.
    if (l == 63) out[pair] = K[2];
}

extern "C" void kernel_launch(void* const* d_in, const int* in_sizes, int n_in,
                              void* d_out, int out_size, void* d_ws, size_t ws_size,
                              hipStream_t stream)
{
    const float* X = (const float*)d_in[0];
    const float* Y = (const float*)d_in[1];
    float* out = (float*)d_out;
    (void)in_sizes; (void)n_in; (void)out_size; (void)d_ws; (void)ws_size;

    sigker_strip<<<dim3(32 * 32), dim3(64), 0, stream>>>(X, Y, out);
}

// Round 3
// 46.171 us; speedup vs baseline: 3.5203x; 1.5292x over previous
//
#include <hip/hip_runtime.h>

// SigKernel: X (32,256,8) f32, Y (32,256,8) f32 -> out (32,32) f32.
// refinement=1.0 => interpolation identity; scale=1.0 => a_ij = dot(dX[i-1], dY[j-1]).
// Goursat PDE on 256x256 grid, boundary K[i][0]=K[0][j]=1:
//   f1 = 1 + a/2 + a^2/12, f2 = 1 - a^2/12
//   K[i][j] = (K[i][j-1] + K[i-1][j])*f1 - K[i-1][j-1]*f2 ; out = K[255][255]
//
// 1 wave per pair, lane l owns rows 4l+1..4l+4, skewed column march (step s,
// lane l handles column j = s-l). Inter-lane dep via __shfl_up, no barriers.
// Branch-free: dYs zero-padded so j<1 / j>255 steps are harmless identity
// updates (dy=0 -> f1=f2=1 -> K+up-upd keeps boundary 1, past-end unread).
// Row-packed float2 math -> v_pk_fma_f32 (the only path to fp32 peak).

typedef float f32x2 __attribute__((ext_vector_type(2)));
typedef float f32x4 __attribute__((ext_vector_type(4)));

#define MM   255
#define DYST 9            // odd float stride -> conflict-free b32 reads
#define DYSZ 3456         // >= (318+63)*9+8+1 = 3437, rounded to 64*54

static __device__ inline f32x2 fma2(f32x2 a, f32x2 b, f32x2 c) {
    return __builtin_elementwise_fma(a, b, c);
}

__global__ __launch_bounds__(64) void sigker_strip3(
    const float* __restrict__ X,
    const float* __restrict__ Y,
    float* __restrict__ out)
{
    const int pair = blockIdx.x;      // 0..1023
    const int ax = pair >> 5;
    const int by = pair & 31;
    const int l  = threadIdx.x;       // 0..63

    __shared__ float dYs[DYSZ];

    const float* Xa = X + ax * 2048;
    const float* Yb = Y + by * 2048;

    // Zero-fill (pads), then real dY increments at (j+63)*9 + c, j in [0,254].
    #pragma unroll 6
    for (int v = l; v < DYSZ; v += 64) dYs[v] = 0.0f;
    __syncthreads();
    for (int v = l; v < MM * 8; v += 64) {
        const int j = v >> 3, c = v & 7;
        dYs[(j + 63) * DYST + c] = Yb[(j + 1) * 8 + c] - Yb[j * 8 + c];
    }

    // dx rows 4l+1..4l+4 from a contiguous 40-float window [4l*8, 4l*8+40).
    // Lane 63's window tail (row 256) is OOB -> zero (its K3 is never read).
    f32x4 f[10];
    const f32x4* Xv = (const f32x4*)(Xa + l * 32);
    #pragma unroll
    for (int k = 0; k < 8; ++k) f[k] = Xv[k];
    f[8] = (l < 63) ? Xv[8] : (f32x4)0.0f;
    f[9] = (l < 63) ? Xv[9] : (f32x4)0.0f;

    f32x2 dxp0[8], dxp1[8];   // {row r0,r1} and {row r2,r3} per dim
    #pragma unroll
    for (int c = 0; c < 8; ++c) {
        const float e0 = f[(c)      >> 2][(c)      & 3];
        const float e1 = f[(8 + c)  >> 2][(8 + c)  & 3];
        const float e2 = f[(16 + c) >> 2][(16 + c) & 3];
        const float e3 = f[(24 + c) >> 2][(24 + c) & 3];
        const float e4 = f[(32 + c) >> 2][(32 + c) & 3];
        dxp0[c] = (f32x2){e1 - e0, e2 - e1};
        dxp1[c] = (f32x2){e3 - e2, e4 - e3};
    }

    __syncthreads();

    const f32x2 C12  = { 1.0f / 12.0f,  1.0f / 12.0f};
    const f32x2 CN12 = {-1.0f / 12.0f, -1.0f / 12.0f};
    const f32x2 CH   = { 0.5f, 0.5f};
    const f32x2 C1   = { 1.0f, 1.0f};

    float K0 = 1.0f, K1 = 1.0f, K2 = 1.0f, K3 = 1.0f, upd = 1.0f;

    int base = (63 - l) * DYST;       // idx(s=1) = (s-1-l+63)*9
    float dy0 = dYs[base + 0], dy1 = dYs[base + 1];
    float dy2 = dYs[base + 2], dy3 = dYs[base + 3];
    float dy4 = dYs[base + 4], dy5 = dYs[base + 5];
    float dy6 = dYs[base + 6], dy7 = dYs[base + 7];

    #pragma unroll 2
    for (int s = 1; s <= MM + 63; ++s) {      // 318 steps
        // Prefetch next step's dy (unconditional, zero-padded).
        const int nb = base + DYST;
        const float ny0 = dYs[nb + 0], ny1 = dYs[nb + 1];
        const float ny2 = dYs[nb + 2], ny3 = dYs[nb + 3];
        const float ny4 = dYs[nb + 4], ny5 = dYs[nb + 5];
        const float ny6 = dYs[nb + 6], ny7 = dYs[nb + 7];

        float up = __shfl_up(K3, 1);          // lane l-1's row-4l value @ col j
        if (l == 0) up = 1.0f;                // row-0 boundary

        // Packed dots: a01 = {a(r0), a(r1)}, a23 = {a(r2), a(r3)}.
        f32x2 b;
        b = (f32x2){dy0, dy0};
        f32x2 a01 = dxp0[0] * b, a23 = dxp1[0] * b;
        b = (f32x2){dy1, dy1};
        a01 = fma2(dxp0[1], b, a01); a23 = fma2(dxp1[1], b, a23);
        b = (f32x2){dy2, dy2};
        a01 = fma2(dxp0[2], b, a01); a23 = fma2(dxp1[2], b, a23);
        b = (f32x2){dy3, dy3};
        a01 = fma2(dxp0[3], b, a01); a23 = fma2(dxp1[3], b, a23);
        b = (f32x2){dy4, dy4};
        a01 = fma2(dxp0[4], b, a01); a23 = fma2(dxp1[4], b, a23);
        b = (f32x2){dy5, dy5};
        a01 = fma2(dxp0[5], b, a01); a23 = fma2(dxp1[5], b, a23);
        b = (f32x2){dy6, dy6};
        a01 = fma2(dxp0[6], b, a01); a23 = fma2(dxp1[6], b, a23);
        b = (f32x2){dy7, dy7};
        a01 = fma2(dxp0[7], b, a01); a23 = fma2(dxp1[7], b, a23);

        const f32x2 q01 = a01 * a01, q23 = a23 * a23;
        const f32x2 f1a = fma2(q01, C12, fma2(a01, CH, C1));
        const f32x2 f1b = fma2(q23, C12, fma2(a23, CH, C1));
        const f32x2 f2a = fma2(q01, CN12, C1);
        const f32x2 f2b = fma2(q23, CN12, C1);

        // Serial 4-cell recurrence (kupd for row r = old K[r-1]; row 0: upd).
        const float t0 = upd * f2a.x;
        const float k0 = fmaf(K0 + up, f1a.x, -t0);
        const float t1 = K0 * f2a.y;
        const float k1 = fmaf(K1 + k0, f1a.y, -t1);
        const float t2 = K1 * f2b.x;
        const float k2 = fmaf(K2 + k1, f1b.x, -t2);
        const float t3 = K2 * f2b.y;
        const float k3 = fmaf(K3 + k2, f1b.y, -t3);

        upd = up; K0 = k0; K1 = k1; K2 = k2; K3 = k3;
        dy0 = ny0; dy1 = ny1; dy2 = ny2; dy3 = ny3;
        dy4 = ny4; dy5 = ny5; dy6 = ny6; dy7 = ny7;
        base = nb;
    }

    // Row 255 = lane 63, local r=2; last real update at s=318 (j=255).
    if (l == 63) out[pair] = K2;
}

extern "C" void kernel_launch(void* const* d_in, const int* in_sizes, int n_in,
                              void* d_out, int out_size, void* d_ws, size_t ws_size,
                              hipStream_t stream)
{
    const float* X = (const float*)d_in[0];
    const float* Y = (const float*)d_in[1];
    float* out = (float*)d_out;
    (void)in_sizes; (void)n_in; (void)out_size; (void)d_ws; (void)ws_size;

    sigker_strip3<<<dim3(32 * 32), dim3(64), 0, stream>>>(X, Y, out);
}